// Round 2
// baseline (2133.234 us; speedup 1.0000x reference)
//
#include <hip/hip_runtime.h>

typedef unsigned short u16;
typedef short s16x8 __attribute__((ext_vector_type(8)));
typedef float f32x4 __attribute__((ext_vector_type(4)));

__device__ __forceinline__ float bf2f(u16 v) {
    return __uint_as_float(((unsigned int)v) << 16);
}
__device__ __forceinline__ u16 f2bf(float f) {
    unsigned int u = __float_as_uint(f);
    u = u + 0x7FFFu + ((u >> 16) & 1u);
    return (u16)(u >> 16);
}
__device__ __forceinline__ f32x4 mfma16(s16x8 a, s16x8 b, f32x4 c) {
    return __builtin_amdgcn_mfma_f32_16x16x32_bf16(a, b, c, 0, 0, 0);
}
#define ZERO4 f32x4{0.f, 0.f, 0.f, 0.f}

// ============ prepack: f32 weights -> bf16 MFMA B-fragment layouts ============
// Bp[n][k'], k' = (ic*9 + kx*3 + ky)*4 + kz', kz'=3 slot zeroed (K pad 3->4)
// WkvP[n(512)][c], WqP[n][c], W1T[h][c], W2T[d][h]  (all [out][in]-contig)
__global__ void prepack_kernel(const float* __restrict__ conv_w, const float* __restrict__ Wk,
                               const float* __restrict__ Wv, const float* __restrict__ Wq,
                               const float* __restrict__ W1, const float* __restrict__ W2,
                               u16* __restrict__ Bp, u16* __restrict__ WkvP, u16* __restrict__ WqP,
                               u16* __restrict__ W1T, u16* __restrict__ W2T)
{
    int idx = blockIdx.x * 256 + threadIdx.x;
    if (idx < 294912) {                       // 256 n * 1152 groups
        int n = idx / 1152, g = idx - n * 1152;
        int ic = g / 9, r = g - ic * 9;       // r = kx*3+ky
        const float* s = conv_w + n * 3456 + ic * 27 + r * 3;
        u16* d = Bp + n * 4608 + g * 4;
        d[0] = f2bf(s[0]); d[1] = f2bf(s[1]); d[2] = f2bf(s[2]); d[3] = 0;
    } else if (idx < 425984) {                // WkvP 512*256
        int i = idx - 294912;
        int n = i >> 8, c = i & 255;
        WkvP[i] = f2bf((n < 256) ? Wk[c * 256 + n] : Wv[c * 256 + (n - 256)]);
    } else if (idx < 491520) {                // WqP 256*256
        int i = idx - 425984;
        int n = i >> 8, c = i & 255;
        WqP[i] = f2bf(Wq[c * 256 + n]);
    } else if (idx < 622592) {                // W1T 512*256
        int i = idx - 491520;
        int h = i >> 8, c = i & 255;
        W1T[i] = f2bf(W1[c * 512 + h]);
    } else if (idx < 753664) {                // W2T 256*512
        int i = idx - 622592;
        int dd = i >> 9, h = i & 511;
        W2T[i] = f2bf(W2[h * 256 + dd]);
    }
}

// ============ init templates f32 (broadcast over batch) ============
__global__ void init_templates(const float* __restrict__ tinit, float* __restrict__ tpl)
{
    int idx = blockIdx.x * 256 + threadIdx.x;   // < 131072
    tpl[idx] = tinit[idx & 16383];
}

// ============ fused conv3d(s2)+bias+ReLU+LN_in + k/v GEMM ============
// grid 512 = b(8) * ox(16) * oyb(4); block 256 (4 waves)
// M-tile = 64 tokens (oy_l 0..3 x oz 0..15), N = 256 oc; K' = 4608
__global__ __launch_bounds__(256, 2) void conv_fused(
    const float* __restrict__ x, const u16* __restrict__ Bp, const float* __restrict__ conv_b,
    const float* __restrict__ ln_g, const float* __restrict__ ln_b, const u16* __restrict__ WkvP,
    u16* __restrict__ kbuf, u16* __restrict__ vT)
{
    __shared__ __align__(16) char smem[35328];
    u16* slab   = (u16*)smem;                 // [16 ic][3 ix][9 iy][36 iz] = 31104 B
    u16* tokbf  = (u16*)smem;                 // alias: [64 m][256 c] bf16 = 32768 B
    float* lnred  = (float*)(smem + 32768);   // [4 w][64 m][2]
    float* lnstat = (float*)(smem + 34816);   // [64 m][2]

    int blk = blockIdx.x;
    int b = blk >> 6, ox = (blk >> 2) & 15, oyb = blk & 3;
    int tid = threadIdx.x, wid = tid >> 6, lane = tid & 63;
    int quad = lane >> 4, l15 = lane & 15;
    int nbase = wid * 64;

    f32x4 acc[4][4];
    #pragma unroll
    for (int i = 0; i < 4; ++i)
        #pragma unroll
        for (int j = 0; j < 4; ++j) acc[i][j] = ZERO4;

    for (int icc = 0; icc < 8; ++icc) {
        __syncthreads();
        for (int idx = tid; idx < 15552; idx += 256) {
            int row = idx / 36, col = idx - row * 36;
            u16 v = 0;
            if (col < 33) {
                int icl = row / 27, rr = row - icl * 27;
                int ixl = rr / 9, iyl = rr - ixl * 9;
                v = f2bf(x[((b * 128 + icc * 16 + icl) * 33 + (2 * ox + ixl)) * 1089
                           + (8 * oyb + iyl) * 33 + col]);
            }
            slab[idx] = v;   // cols 33..35 zeroed (pad lane safety)
        }
        __syncthreads();
        #pragma unroll 1
        for (int c8 = 0; c8 < 18; ++c8) {
            int k0 = icc * 576 + c8 * 32;
            s16x8 bfr[4];
            #pragma unroll
            for (int fn = 0; fn < 4; ++fn)
                bfr[fn] = *reinterpret_cast<const s16x8*>(
                    Bp + (nbase + fn * 16 + l15) * 4608 + k0 + quad * 8);
            int base0, base1;
            {
                int g = c8 * 8 + quad * 2;
                int icl = g / 9, r9 = g - icl * 9, kx = r9 / 3, ky = r9 - kx * 3;
                base0 = (icl * 3 + kx) * 324 + ky * 36 + 2 * l15;
                g += 1;
                icl = g / 9; r9 = g - icl * 9; kx = r9 / 3; ky = r9 - kx * 3;
                base1 = (icl * 3 + kx) * 324 + ky * 36 + 2 * l15;
            }
            #pragma unroll
            for (int fm = 0; fm < 4; ++fm) {
                union { s16x8 v; ushort2 h[4]; } af;
                const u16* sp0 = slab + base0 + fm * 72;
                const u16* sp1 = slab + base1 + fm * 72;
                af.h[0] = *(const ushort2*)(sp0);
                af.h[1] = *(const ushort2*)(sp0 + 2);
                af.h[2] = *(const ushort2*)(sp1);
                af.h[3] = *(const ushort2*)(sp1 + 2);
                #pragma unroll
                for (int fn = 0; fn < 4; ++fn)
                    acc[fm][fn] = mfma16(af.v, bfr[fn], acc[fm][fn]);
            }
        }
    }
    // ---- bias + relu ----
    #pragma unroll
    for (int fn = 0; fn < 4; ++fn) {
        float bias = conv_b[nbase + fn * 16 + l15];
        #pragma unroll
        for (int fm = 0; fm < 4; ++fm)
            #pragma unroll
            for (int r = 0; r < 4; ++r)
                acc[fm][fn][r] = fmaxf(acc[fm][fn][r] + bias, 0.f);
    }
    // ---- LN_in: reduce over c=256 per token ----
    #pragma unroll
    for (int fm = 0; fm < 4; ++fm) {
        #pragma unroll
        for (int r = 0; r < 4; ++r) {
            float s = acc[fm][0][r] + acc[fm][1][r] + acc[fm][2][r] + acc[fm][3][r];
            float q2 = acc[fm][0][r] * acc[fm][0][r] + acc[fm][1][r] * acc[fm][1][r]
                     + acc[fm][2][r] * acc[fm][2][r] + acc[fm][3][r] * acc[fm][3][r];
            #pragma unroll
            for (int msk = 1; msk <= 8; msk <<= 1) {
                s  += __shfl_xor(s, msk, 64);
                q2 += __shfl_xor(q2, msk, 64);
            }
            if (l15 == 0) {
                int mm = fm * 16 + quad * 4 + r;
                lnred[(wid * 64 + mm) * 2 + 0] = s;
                lnred[(wid * 64 + mm) * 2 + 1] = q2;
            }
        }
    }
    __syncthreads();
    if (tid < 64) {
        float s = 0, q2 = 0;
        #pragma unroll
        for (int w = 0; w < 4; ++w) { s += lnred[(w * 64 + tid) * 2]; q2 += lnred[(w * 64 + tid) * 2 + 1]; }
        float mu = s * (1.f / 256.f);
        float var = fmaxf(q2 * (1.f / 256.f) - mu * mu, 0.f);
        lnstat[tid * 2]     = mu;
        lnstat[tid * 2 + 1] = rsqrtf(var + 1e-5f);
    }
    __syncthreads();
    {   // normalize -> tokbf (aliases slab; safe after two barriers)
        float gam[4], bet[4];
        #pragma unroll
        for (int fn = 0; fn < 4; ++fn) {
            int n = nbase + fn * 16 + l15;
            gam[fn] = ln_g[n]; bet[fn] = ln_b[n];
        }
        #pragma unroll
        for (int fm = 0; fm < 4; ++fm)
            #pragma unroll
            for (int r = 0; r < 4; ++r) {
                int mm = fm * 16 + quad * 4 + r;
                float mu = lnstat[mm * 2], rs = lnstat[mm * 2 + 1];
                #pragma unroll
                for (int fn = 0; fn < 4; ++fn) {
                    int n = nbase + fn * 16 + l15;
                    tokbf[mm * 256 + n] = f2bf((acc[fm][fn][r] - mu) * rs * gam[fn] + bet[fn]);
                }
            }
    }
    __syncthreads();
    // ---- k/v GEMM: [64 m]x[512 n], K=256 ----
    f32x4 kacc[4][8];
    #pragma unroll
    for (int i = 0; i < 4; ++i)
        #pragma unroll
        for (int j = 0; j < 8; ++j) kacc[i][j] = ZERO4;
    int n2 = wid * 128;
    #pragma unroll 1
    for (int kc = 0; kc < 8; ++kc) {
        s16x8 a2[4];
        #pragma unroll
        for (int fm = 0; fm < 4; ++fm)
            a2[fm] = *reinterpret_cast<const s16x8*>(tokbf + (fm * 16 + l15) * 256 + kc * 32 + quad * 8);
        #pragma unroll
        for (int fn = 0; fn < 8; ++fn) {
            s16x8 bv = *reinterpret_cast<const s16x8*>(WkvP + (n2 + fn * 16 + l15) * 256 + kc * 32 + quad * 8);
            #pragma unroll
            for (int fm = 0; fm < 4; ++fm)
                kacc[fm][fn] = mfma16(a2[fm], bv, kacc[fm][fn]);
        }
    }
    #pragma unroll
    for (int fm = 0; fm < 4; ++fm)
        #pragma unroll
        for (int r = 0; r < 4; ++r) {
            int mm = fm * 16 + quad * 4 + r;
            int l = (ox * 16 + oyb * 4 + (mm >> 4)) * 16 + (mm & 15);
            #pragma unroll
            for (int fn = 0; fn < 8; ++fn) {
                int n = n2 + fn * 16 + l15;
                u16 v = f2bf(kacc[fm][fn][r]);
                if (n < 256) kbuf[((b << 12) + l) * 256 + n] = v;           // k[b][l][d]
                else         vT[((b * 256 + (n - 256)) << 12) + l] = v;     // vT[b][d][l]
            }
        }
}

// ============ kA: zero colsum, LN_t(templates), q = LN(t)@Wq * scale ============
__global__ __launch_bounds__(256) void kA(
    const float* __restrict__ tpl, const float* __restrict__ ln_t_g, const float* __restrict__ ln_t_b,
    const u16* __restrict__ WqP, u16* __restrict__ qbuf, float* __restrict__ colsum)
{
    __shared__ __align__(16) u16 tbf[16384];
    __shared__ float pls[64][4][2];
    __shared__ float stat[64][2];
    int b = blockIdx.x, tid = threadIdx.x;
    if (tid < 64) colsum[b * 64 + tid] = 0.f;
    int m = tid >> 2, part = tid & 3;
    const float* tp = tpl + (b * 64 + m) * 256 + part * 64;
    float s = 0, q2 = 0;
    for (int i = 0; i < 64; ++i) { float v = tp[i]; s += v; q2 += v * v; }
    pls[m][part][0] = s; pls[m][part][1] = q2;
    __syncthreads();
    if (tid < 64) {
        float ss = 0, qq = 0;
        #pragma unroll
        for (int p = 0; p < 4; ++p) { ss += pls[tid][p][0]; qq += pls[tid][p][1]; }
        float mu = ss * (1.f / 256.f);
        float var = fmaxf(qq * (1.f / 256.f) - mu * mu, 0.f);
        stat[tid][0] = mu; stat[tid][1] = rsqrtf(var + 1e-5f);
    }
    __syncthreads();
    {
        float mu = stat[m][0], rs = stat[m][1];
        for (int i = 0; i < 64; ++i) {
            int d = part * 64 + i;
            tbf[m * 256 + d] = f2bf((tp[i] - mu) * rs * ln_t_g[d] + ln_t_b[d]);
        }
    }
    __syncthreads();
    int wid = tid >> 6, lane = tid & 63, quad = lane >> 4, l15 = lane & 15;
    f32x4 qa[4][4];
    #pragma unroll
    for (int i = 0; i < 4; ++i)
        #pragma unroll
        for (int j = 0; j < 4; ++j) qa[i][j] = ZERO4;
    #pragma unroll 1
    for (int kc = 0; kc < 8; ++kc) {
        s16x8 a[4];
        #pragma unroll
        for (int fm = 0; fm < 4; ++fm)
            a[fm] = *reinterpret_cast<const s16x8*>(tbf + (fm * 16 + l15) * 256 + kc * 32 + quad * 8);
        #pragma unroll
        for (int fn = 0; fn < 4; ++fn) {
            s16x8 bv = *reinterpret_cast<const s16x8*>(WqP + (wid * 64 + fn * 16 + l15) * 256 + kc * 32 + quad * 8);
            #pragma unroll
            for (int fm = 0; fm < 4; ++fm)
                qa[fm][fn] = mfma16(a[fm], bv, qa[fm][fn]);
        }
    }
    #pragma unroll
    for (int fm = 0; fm < 4; ++fm)
        #pragma unroll
        for (int fn = 0; fn < 4; ++fn)
            #pragma unroll
            for (int r = 0; r < 4; ++r) {
                int mt = fm * 16 + quad * 4 + r;
                int d = wid * 64 + fn * 16 + l15;
                qbuf[(b * 64 + mt) * 256 + d] = f2bf(qa[fm][fn][r] * 0.0625f);
            }
}

// ============ kB: logits + softmax(over N) + 1e-8 + colsum + attnT store ============
// grid 512 = b(8) * lt(64); tile: 64 l x 64 n
__global__ __launch_bounds__(256) void kB(
    const u16* __restrict__ qbuf, const u16* __restrict__ kbuf,
    u16* __restrict__ attnT, float* __restrict__ colsum)
{
    __shared__ __align__(16) u16 atile[64 * 72];
    int blk = blockIdx.x;
    int b = blk >> 6, lt = blk & 63;
    int tid = threadIdx.x, wid = tid >> 6, lane = tid & 63;
    int quad = lane >> 4, l15 = lane & 15;
    f32x4 sa[4];
    #pragma unroll
    for (int fn = 0; fn < 4; ++fn) sa[fn] = ZERO4;
    const u16* arow = kbuf + ((b << 12) + lt * 64 + wid * 16 + l15) * 256;
    const u16* qb = qbuf + b * 16384;
    #pragma unroll 1
    for (int kc = 0; kc < 8; ++kc) {
        s16x8 a = *reinterpret_cast<const s16x8*>(arow + kc * 32 + quad * 8);
        #pragma unroll
        for (int fn = 0; fn < 4; ++fn) {
            s16x8 bv = *reinterpret_cast<const s16x8*>(qb + (fn * 16 + l15) * 256 + kc * 32 + quad * 8);
            sa[fn] = mfma16(a, bv, sa[fn]);
        }
    }
    float colp[4] = {0.f, 0.f, 0.f, 0.f};
    #pragma unroll
    for (int r = 0; r < 4; ++r) {
        float mx = fmaxf(fmaxf(sa[0][r], sa[1][r]), fmaxf(sa[2][r], sa[3][r]));
        #pragma unroll
        for (int msk = 1; msk <= 8; msk <<= 1) mx = fmaxf(mx, __shfl_xor(mx, msk, 64));
        float e[4], sum = 0;
        #pragma unroll
        for (int fn = 0; fn < 4; ++fn) { e[fn] = __expf(sa[fn][r] - mx); sum += e[fn]; }
        #pragma unroll
        for (int msk = 1; msk <= 8; msk <<= 1) sum += __shfl_xor(sum, msk, 64);
        float inv = 1.f / sum;
        #pragma unroll
        for (int fn = 0; fn < 4; ++fn) {
            float p = e[fn] * inv + 1e-8f;
            sa[fn][r] = p;
            colp[fn] += p;
        }
    }
    #pragma unroll
    for (int fn = 0; fn < 4; ++fn) {
        float c = colp[fn];
        c += __shfl_xor(c, 16, 64);
        c += __shfl_xor(c, 32, 64);
        colp[fn] = c;
    }
    if (lane < 16) {
        #pragma unroll
        for (int fn = 0; fn < 4; ++fn)
            atomicAdd(&colsum[b * 64 + fn * 16 + lane], colp[fn]);
    }
    #pragma unroll
    for (int r = 0; r < 4; ++r)
        #pragma unroll
        for (int fn = 0; fn < 4; ++fn)
            atile[(fn * 16 + l15) * 72 + wid * 16 + quad * 4 + r] = f2bf(sa[fn][r]);
    __syncthreads();
    int n = tid >> 2, lo = (tid & 3) * 16;
    const u16* src = atile + n * 72 + lo;
    u16* dst = attnT + ((b * 64 + n) << 12) + lt * 64 + lo;
    *(int4*)dst = *(const int4*)src;
    *(int4*)(dst + 8) = *(const int4*)(src + 8);
}

// ============ kC: delta partials = attnT @ vT^T over l-segment ============
// grid 128 = b(8) * seg(16); per wg: M=64 n_t, N=256 d, K=256 l
__global__ __launch_bounds__(256) void kC(
    const u16* __restrict__ attnT, const u16* __restrict__ vT, float* __restrict__ pbuf)
{
    int blk = blockIdx.x;
    int b = blk >> 4, seg = blk & 15;
    int tid = threadIdx.x, wid = tid >> 6, lane = tid & 63;
    int quad = lane >> 4, l15 = lane & 15;
    f32x4 acc[4][4];
    #pragma unroll
    for (int i = 0; i < 4; ++i)
        #pragma unroll
        for (int j = 0; j < 4; ++j) acc[i][j] = ZERO4;
    #pragma unroll 1
    for (int kc = 0; kc < 8; ++kc) {
        int koff = seg * 256 + kc * 32 + quad * 8;
        s16x8 a[4];
        #pragma unroll
        for (int fm = 0; fm < 4; ++fm)
            a[fm] = *reinterpret_cast<const s16x8*>(attnT + ((b * 64 + fm * 16 + l15) << 12) + koff);
        #pragma unroll
        for (int fn = 0; fn < 4; ++fn) {
            s16x8 bv = *reinterpret_cast<const s16x8*>(vT + ((b * 256 + wid * 64 + fn * 16 + l15) << 12) + koff);
            #pragma unroll
            for (int fm = 0; fm < 4; ++fm)
                acc[fm][fn] = mfma16(a[fm], bv, acc[fm][fn]);
        }
    }
    #pragma unroll
    for (int fm = 0; fm < 4; ++fm)
        #pragma unroll
        for (int fn = 0; fn < 4; ++fn)
            #pragma unroll
            for (int r = 0; r < 4; ++r) {
                int nt = fm * 16 + quad * 4 + r;
                int d = wid * 64 + fn * 16 + l15;
                pbuf[((b * 16 + seg) * 64 + nt) * 256 + d] = acc[fm][fn][r];
            }
}

// ============ kD1: templates += delta/colsum; LN_m -> mbuf ============
__global__ __launch_bounds__(256) void kD1(
    float* __restrict__ tpl, const float* __restrict__ pbuf, const float* __restrict__ colsum,
    const float* __restrict__ ln_m_g, const float* __restrict__ ln_m_b, u16* __restrict__ mbuf)
{
    __shared__ float pls[64][4][2];
    __shared__ float stat[64][2];
    int b = blockIdx.x, tid = threadIdx.x;
    int m = tid >> 2, part = tid & 3;
    float cinv = 1.f / colsum[b * 64 + m];
    float* tg = tpl + (b * 64 + m) * 256 + part * 64;
    const float* pb = pbuf + b * 262144 + m * 256 + part * 64;
    float s = 0, q2 = 0;
    for (int i = 0; i < 64; ++i) {
        float ds = 0;
        #pragma unroll
        for (int g = 0; g < 16; ++g) ds += pb[g * 16384 + i];
        float v = tg[i] + ds * cinv;
        s += v; q2 += v * v;
    }
    pls[m][part][0] = s; pls[m][part][1] = q2;
    __syncthreads();
    if (tid < 64) {
        float ss = 0, qq = 0;
        #pragma unroll
        for (int p = 0; p < 4; ++p) { ss += pls[tid][p][0]; qq += pls[tid][p][1]; }
        float mu = ss * (1.f / 256.f);
        float var = fmaxf(qq * (1.f / 256.f) - mu * mu, 0.f);
        stat[tid][0] = mu; stat[tid][1] = rsqrtf(var + 1e-5f);
    }
    __syncthreads();
    float mu = stat[m][0], rs = stat[m][1];
    for (int i = 0; i < 64; ++i) {
        float ds = 0;
        #pragma unroll
        for (int g = 0; g < 16; ++g) ds += pb[g * 16384 + i];
        float v = tg[i] + ds * cinv;
        tg[i] = v;                                 // templates = t_prev + delta
        int d = part * 64 + i;
        mbuf[(b * 64 + m) * 256 + d] = f2bf((v - mu) * rs * ln_m_g[d] + ln_m_b[d]);
    }
}

// ============ kD2: MLP (gelu exact) + templates += mlp; final out0 write ============
__global__ __launch_bounds__(256) void kD2(
    float* __restrict__ tpl, const u16* __restrict__ mbuf,
    const u16* __restrict__ W1T, const float* __restrict__ b1,
    const u16* __restrict__ W2T, const float* __restrict__ b2,
    int last, float* __restrict__ out0)
{
    __shared__ __align__(16) u16 hid[64 * 512];   // 64 KiB
    int b = blockIdx.x, tid = threadIdx.x, wid = tid >> 6, lane = tid & 63;
    int quad = lane >> 4, l15 = lane & 15;
    const u16* mb = mbuf + b * 16384;
    {
        f32x4 ha[4][8];
        #pragma unroll
        for (int i = 0; i < 4; ++i)
            #pragma unroll
            for (int j = 0; j < 8; ++j) ha[i][j] = ZERO4;
        #pragma unroll 1
        for (int kc = 0; kc < 8; ++kc) {
            s16x8 a[4];
            #pragma unroll
            for (int fm = 0; fm < 4; ++fm)
                a[fm] = *reinterpret_cast<const s16x8*>(mb + (fm * 16 + l15) * 256 + kc * 32 + quad * 8);
            #pragma unroll
            for (int fn = 0; fn < 8; ++fn) {
                s16x8 bv = *reinterpret_cast<const s16x8*>(W1T + (wid * 128 + fn * 16 + l15) * 256 + kc * 32 + quad * 8);
                #pragma unroll
                for (int fm = 0; fm < 4; ++fm)
                    ha[fm][fn] = mfma16(a[fm], bv, ha[fm][fn]);
            }
        }
        #pragma unroll
        for (int fm = 0; fm < 4; ++fm)
            #pragma unroll
            for (int fn = 0; fn < 8; ++fn) {
                int nh = wid * 128 + fn * 16 + l15;
                float bb = b1[nh];
                #pragma unroll
                for (int r = 0; r < 4; ++r) {
                    int mm = fm * 16 + quad * 4 + r;
                    float v = ha[fm][fn][r] + bb;
                    v = 0.5f * v * (1.f + erff(v * 0.70710678118654752f));
                    hid[mm * 512 + nh] = f2bf(v);
                }
            }
    }
    __syncthreads();
    {
        f32x4 oa[4][4];
        #pragma unroll
        for (int i = 0; i < 4; ++i)
            #pragma unroll
            for (int j = 0; j < 4; ++j) oa[i][j] = ZERO4;
        #pragma unroll 1
        for (int kc = 0; kc < 16; ++kc) {
            s16x8 a[4];
            #pragma unroll
            for (int fm = 0; fm < 4; ++fm)
                a[fm] = *reinterpret_cast<const s16x8*>(hid + (fm * 16 + l15) * 512 + kc * 32 + quad * 8);
            #pragma unroll
            for (int fn = 0; fn < 4; ++fn) {
                s16x8 bv = *reinterpret_cast<const s16x8*>(W2T + (wid * 64 + fn * 16 + l15) * 512 + kc * 32 + quad * 8);
                #pragma unroll
                for (int fm = 0; fm < 4; ++fm)
                    oa[fm][fn] = mfma16(a[fm], bv, oa[fm][fn]);
            }
        }
        #pragma unroll
        for (int fm = 0; fm < 4; ++fm)
            #pragma unroll
            for (int fn = 0; fn < 4; ++fn) {
                int d = wid * 64 + fn * 16 + l15;
                float bb = b2[d];
                #pragma unroll
                for (int r = 0; r < 4; ++r) {
                    int mm = fm * 16 + quad * 4 + r;
                    float v = oa[fm][fn][r] + bb;
                    float old = atomicAdd(&tpl[(b * 64 + mm) * 256 + d], v);
                    if (last) out0[(b * 256 + d) * 64 + mm] = old + v;
                }
            }
    }
}

// ============ kE: attn_out = attnT / colsum ============
__global__ void kE(const u16* __restrict__ attnT, const float* __restrict__ colsum,
                   float* __restrict__ out1)
{
    int idx = blockIdx.x * 256 + threadIdx.x;   // < 2097152
    int b = idx >> 18, n = (idx >> 12) & 63;
    out1[idx] = bf2f(attnT[idx]) * (1.f / colsum[b * 64 + n]);
}

// ============ launch ============
extern "C" void kernel_launch(void* const* d_in, const int* in_sizes, int n_in,
                              void* d_out, int out_size, void* d_ws, size_t ws_size,
                              hipStream_t stream)
{
    const float* x       = (const float*)d_in[0];
    const float* tinit   = (const float*)d_in[1];
    const float* conv_w  = (const float*)d_in[2];
    const float* conv_b  = (const float*)d_in[3];
    const float* Wq      = (const float*)d_in[4];
    const float* Wk      = (const float*)d_in[5];
    const float* Wv      = (const float*)d_in[6];
    const float* ln_in_g = (const float*)d_in[7];
    const float* ln_in_b = (const float*)d_in[8];
    const float* ln_t_g  = (const float*)d_in[9];
    const float* ln_t_b  = (const float*)d_in[10];
    const float* ln_m_g  = (const float*)d_in[11];
    const float* ln_m_b  = (const float*)d_in[12];
    const float* W1      = (const float*)d_in[13];
    const float* b1      = (const float*)d_in[14];
    const float* W2      = (const float*)d_in[15];
    const float* b2      = (const float*)d_in[16];

    char* ws = (char*)d_ws;
    u16* Bp       = (u16*)(ws + 0);          // 2,359,296
    u16* WkvP     = (u16*)(ws + 2359296);    //   262,144
    u16* WqP      = (u16*)(ws + 2621440);    //   131,072
    u16* W1T      = (u16*)(ws + 2752512);    //   262,144
    u16* W2T      = (u16*)(ws + 3014656);    //   262,144
    u16* kbuf     = (u16*)(ws + 3276800);    // 16,777,216
    u16* vT       = (u16*)(ws + 20054016);   // 16,777,216
    u16* qbuf     = (u16*)(ws + 36831232);   //   262,144
    u16* attnT    = (u16*)(ws + 37093376);   // 4,194,304
    float* colsum = (float*)(ws + 41287680); //     2,048
    float* tpl    = (float*)(ws + 41289728); //   524,288
    float* pbuf   = (float*)(ws + 41814016); // 8,388,608
    u16* mbuf     = (u16*)(ws + 50202624);   //   262,144   (total ~50.5 MB)

    float* out0 = (float*)d_out;      // templates_out (8,256,64)
    float* out1 = out0 + 131072;      // attn_out (8,64,16,16,16)

    prepack_kernel<<<2944, 256, 0, stream>>>(conv_w, Wk, Wv, Wq, W1, W2, Bp, WkvP, WqP, W1T, W2T);
    init_templates<<<512, 256, 0, stream>>>(tinit, tpl);
    conv_fused<<<512, 256, 0, stream>>>(x, Bp, conv_b, ln_in_g, ln_in_b, WkvP, kbuf, vT);
    for (int it = 0; it < 6; ++it) {
        kA<<<8, 256, 0, stream>>>(tpl, ln_t_g, ln_t_b, WqP, qbuf, colsum);
        kB<<<512, 256, 0, stream>>>(qbuf, kbuf, attnT, colsum);
        kC<<<128, 256, 0, stream>>>(attnT, vT, pbuf);
        kD1<<<8, 256, 0, stream>>>(tpl, pbuf, colsum, ln_m_g, ln_m_b, mbuf);
        kD2<<<8, 256, 0, stream>>>(tpl, mbuf, W1T, b1, W2T, b2, (it == 5) ? 1 : 0, out0);
    }
    kE<<<8192, 256, 0, stream>>>(attnT, colsum, out1);
}

// Round 3
// 1077.783 us; speedup vs baseline: 1.9793x; 1.9793x over previous
//
#include <hip/hip_runtime.h>

typedef unsigned short u16;
typedef short s16x8 __attribute__((ext_vector_type(8)));
typedef float f32x4 __attribute__((ext_vector_type(4)));
typedef float f32x4u __attribute__((ext_vector_type(4), aligned(4)));
typedef unsigned short us4 __attribute__((ext_vector_type(4)));   // 8 B

__device__ __forceinline__ float bf2f(u16 v) {
    return __uint_as_float(((unsigned int)v) << 16);
}
__device__ __forceinline__ u16 f2bf(float f) {
    unsigned int u = __float_as_uint(f);
    u = u + 0x7FFFu + ((u >> 16) & 1u);
    return (u16)(u >> 16);
}
__device__ __forceinline__ f32x4 mfma16(s16x8 a, s16x8 b, f32x4 c) {
    return __builtin_amdgcn_mfma_f32_16x16x32_bf16(a, b, c, 0, 0, 0);
}
#define ZERO4 f32x4{0.f, 0.f, 0.f, 0.f}

// ============ prepack: f32 weights -> bf16 MFMA B-fragment layouts ============
__global__ void prepack_kernel(const float* __restrict__ conv_w, const float* __restrict__ Wk,
                               const float* __restrict__ Wv, const float* __restrict__ Wq,
                               const float* __restrict__ W1, const float* __restrict__ W2,
                               u16* __restrict__ Bp, u16* __restrict__ WkvP, u16* __restrict__ WqP,
                               u16* __restrict__ W1T, u16* __restrict__ W2T)
{
    int idx = blockIdx.x * 256 + threadIdx.x;
    if (idx < 294912) {                       // 256 n * 1152 groups
        int n = idx / 1152, g = idx - n * 1152;
        int ic = g / 9, r = g - ic * 9;
        const float* s = conv_w + n * 3456 + ic * 27 + r * 3;
        u16* d = Bp + n * 4608 + g * 4;
        d[0] = f2bf(s[0]); d[1] = f2bf(s[1]); d[2] = f2bf(s[2]); d[3] = 0;
    } else if (idx < 425984) {                // WkvP 512*256
        int i = idx - 294912;
        int n = i >> 8, c = i & 255;
        WkvP[i] = f2bf((n < 256) ? Wk[c * 256 + n] : Wv[c * 256 + (n - 256)]);
    } else if (idx < 491520) {                // WqP 256*256
        int i = idx - 425984;
        int n = i >> 8, c = i & 255;
        WqP[i] = f2bf(Wq[c * 256 + n]);
    } else if (idx < 622592) {                // W1T 512*256
        int i = idx - 491520;
        int h = i >> 8, c = i & 255;
        W1T[i] = f2bf(W1[c * 512 + h]);
    } else if (idx < 753664) {                // W2T 256*512
        int i = idx - 622592;
        int dd = i >> 9, h = i & 511;
        W2T[i] = f2bf(W2[h * 256 + dd]);
    }
}

// ============ fused conv3d(s2)+bias+ReLU+LN_in + k/v GEMM ============
// grid 512 = b(8) * ox(16) * oyb(4); block 256 (4 waves)
__global__ __launch_bounds__(256, 2) void conv_fused(
    const float* __restrict__ x, const u16* __restrict__ Bp, const float* __restrict__ conv_b,
    const float* __restrict__ ln_g, const float* __restrict__ ln_b, const u16* __restrict__ WkvP,
    u16* __restrict__ kbuf, u16* __restrict__ vT)
{
    __shared__ __align__(16) char smem[36352];
    u16* slab   = (u16*)smem;                 // [16 ic][3 ix][9 iy][36 iz] = 31104 B
    u16* tokbf  = (u16*)smem;                 // alias: [64 m][264 c] bf16 = 33792 B (264-pad: bank fix)
    float* lnred  = (float*)(smem + 33792);   // [4 w][64 m][2] = 2048
    float* lnstat = (float*)(smem + 35840);   // [64 m][2] = 512

    int blk = blockIdx.x;
    int b = blk >> 6, ox = (blk >> 2) & 15, oyb = blk & 3;
    int tid = threadIdx.x, wid = tid >> 6, lane = tid & 63;
    int quad = lane >> 4, l15 = lane & 15;
    int nbase = wid * 64;

    f32x4 acc[4][4];
    #pragma unroll
    for (int i = 0; i < 4; ++i)
        #pragma unroll
        for (int j = 0; j < 4; ++j) acc[i][j] = ZERO4;

    for (int icc = 0; icc < 8; ++icc) {
        __syncthreads();
        // ---- staging: 432 rows x 9 float4-slots, batched loads (latency hiding) ----
        #pragma unroll 1
        for (int half = 0; half < 2; ++half) {
            f32x4u tv[8];
            #pragma unroll
            for (int u = 0; u < 8; ++u) {
                int s = tid + (half * 8 + u) * 256;
                tv[u] = f32x4u{0.f, 0.f, 0.f, 0.f};
                if (s < 3888) {
                    int row = (s * 7282) >> 16;           // s/9
                    int c = s - row * 9;
                    int icl = (row * 2428) >> 16;         // row/27
                    int rr = row - icl * 27;
                    int ixl = (rr * 7282) >> 16;          // rr/9
                    int iyl = rr - ixl * 9;
                    const float* xr = x + ((size_t)((b * 128 + icc * 16 + icl) * 33)
                                           + (2 * ox + ixl)) * 1089 + (8 * oyb + iyl) * 33;
                    if (c < 8) {
                        tv[u] = *(const f32x4u*)(xr + c * 4);
                    } else {
                        tv[u].x = xr[32];                 // col 32; 33..35 stay 0
                    }
                }
            }
            #pragma unroll
            for (int u = 0; u < 8; ++u) {
                int s = tid + (half * 8 + u) * 256;
                if (s < 3888) {
                    int row = (s * 7282) >> 16;
                    int c = s - row * 9;
                    us4 w;
                    w.x = f2bf(tv[u].x); w.y = f2bf(tv[u].y);
                    w.z = f2bf(tv[u].z); w.w = f2bf(tv[u].w);
                    *(us4*)(slab + row * 36 + c * 4) = w;
                }
            }
        }
        __syncthreads();
        #pragma unroll 2
        for (int c8 = 0; c8 < 18; ++c8) {
            int k0 = icc * 576 + c8 * 32;
            s16x8 bfr[4];
            #pragma unroll
            for (int fn = 0; fn < 4; ++fn)
                bfr[fn] = *reinterpret_cast<const s16x8*>(
                    Bp + (nbase + fn * 16 + l15) * 4608 + k0 + quad * 8);
            int base0, base1;
            {
                int g = c8 * 8 + quad * 2;
                int icl = g / 9, r9 = g - icl * 9, kx = r9 / 3, ky = r9 - kx * 3;
                base0 = (icl * 3 + kx) * 324 + ky * 36 + 2 * l15;
                g += 1;
                icl = g / 9; r9 = g - icl * 9; kx = r9 / 3; ky = r9 - kx * 3;
                base1 = (icl * 3 + kx) * 324 + ky * 36 + 2 * l15;
            }
            #pragma unroll
            for (int fm = 0; fm < 4; ++fm) {
                union { s16x8 v; ushort2 h[4]; } af;
                const u16* sp0 = slab + base0 + fm * 72;
                const u16* sp1 = slab + base1 + fm * 72;
                af.h[0] = *(const ushort2*)(sp0);
                af.h[1] = *(const ushort2*)(sp0 + 2);
                af.h[2] = *(const ushort2*)(sp1);
                af.h[3] = *(const ushort2*)(sp1 + 2);
                #pragma unroll
                for (int fn = 0; fn < 4; ++fn)
                    acc[fm][fn] = mfma16(af.v, bfr[fn], acc[fm][fn]);
            }
        }
    }
    // ---- bias + relu ----
    #pragma unroll
    for (int fn = 0; fn < 4; ++fn) {
        float bias = conv_b[nbase + fn * 16 + l15];
        #pragma unroll
        for (int fm = 0; fm < 4; ++fm)
            #pragma unroll
            for (int r = 0; r < 4; ++r)
                acc[fm][fn][r] = fmaxf(acc[fm][fn][r] + bias, 0.f);
    }
    // ---- LN_in ----
    #pragma unroll
    for (int fm = 0; fm < 4; ++fm) {
        #pragma unroll
        for (int r = 0; r < 4; ++r) {
            float s = acc[fm][0][r] + acc[fm][1][r] + acc[fm][2][r] + acc[fm][3][r];
            float q2 = acc[fm][0][r] * acc[fm][0][r] + acc[fm][1][r] * acc[fm][1][r]
                     + acc[fm][2][r] * acc[fm][2][r] + acc[fm][3][r] * acc[fm][3][r];
            #pragma unroll
            for (int msk = 1; msk <= 8; msk <<= 1) {
                s  += __shfl_xor(s, msk, 64);
                q2 += __shfl_xor(q2, msk, 64);
            }
            if (l15 == 0) {
                int mm = fm * 16 + quad * 4 + r;
                lnred[(wid * 64 + mm) * 2 + 0] = s;
                lnred[(wid * 64 + mm) * 2 + 1] = q2;
            }
        }
    }
    __syncthreads();
    if (tid < 64) {
        float s = 0, q2 = 0;
        #pragma unroll
        for (int w = 0; w < 4; ++w) { s += lnred[(w * 64 + tid) * 2]; q2 += lnred[(w * 64 + tid) * 2 + 1]; }
        float mu = s * (1.f / 256.f);
        float var = fmaxf(q2 * (1.f / 256.f) - mu * mu, 0.f);
        lnstat[tid * 2]     = mu;
        lnstat[tid * 2 + 1] = rsqrtf(var + 1e-5f);
    }
    __syncthreads();
    {
        float gam[4], bet[4];
        #pragma unroll
        for (int fn = 0; fn < 4; ++fn) {
            int n = nbase + fn * 16 + l15;
            gam[fn] = ln_g[n]; bet[fn] = ln_b[n];
        }
        #pragma unroll
        for (int fm = 0; fm < 4; ++fm)
            #pragma unroll
            for (int r = 0; r < 4; ++r) {
                int mm = fm * 16 + quad * 4 + r;
                float mu = lnstat[mm * 2], rs = lnstat[mm * 2 + 1];
                #pragma unroll
                for (int fn = 0; fn < 4; ++fn) {
                    int n = nbase + fn * 16 + l15;
                    tokbf[mm * 264 + n] = f2bf((acc[fm][fn][r] - mu) * rs * gam[fn] + bet[fn]);
                }
            }
    }
    __syncthreads();
    // ---- k/v GEMM ----
    f32x4 kacc[4][8];
    #pragma unroll
    for (int i = 0; i < 4; ++i)
        #pragma unroll
        for (int j = 0; j < 8; ++j) kacc[i][j] = ZERO4;
    int n2 = wid * 128;
    #pragma unroll 1
    for (int kc = 0; kc < 8; ++kc) {
        s16x8 a2[4];
        #pragma unroll
        for (int fm = 0; fm < 4; ++fm)
            a2[fm] = *reinterpret_cast<const s16x8*>(tokbf + (fm * 16 + l15) * 264 + kc * 32 + quad * 8);
        #pragma unroll
        for (int fn = 0; fn < 8; ++fn) {
            s16x8 bv = *reinterpret_cast<const s16x8*>(WkvP + (n2 + fn * 16 + l15) * 256 + kc * 32 + quad * 8);
            #pragma unroll
            for (int fm = 0; fm < 4; ++fm)
                kacc[fm][fn] = mfma16(a2[fm], bv, kacc[fm][fn]);
        }
    }
    #pragma unroll
    for (int fm = 0; fm < 4; ++fm)
        #pragma unroll
        for (int r = 0; r < 4; ++r) {
            int mm = fm * 16 + quad * 4 + r;
            int l = (ox * 16 + oyb * 4 + (mm >> 4)) * 16 + (mm & 15);
            #pragma unroll
            for (int fn = 0; fn < 8; ++fn) {
                int n = n2 + fn * 16 + l15;
                u16 v = f2bf(kacc[fm][fn][r]);
                if (n < 256) kbuf[((b << 12) + l) * 256 + n] = v;           // k[b][l][d]
                else         vT[((b * 256 + (n - 256)) << 12) + l] = v;     // vT[b][d][l]
            }
        }
}

// ============ kQ: init tpl, zero colsum/delta, LN_t + q (iter 0) ============
__global__ __launch_bounds__(256) void kQ(
    const float* __restrict__ tinit, float* __restrict__ tpl,
    const float* __restrict__ ln_t_g, const float* __restrict__ ln_t_b,
    const u16* __restrict__ WqP, u16* __restrict__ qbuf,
    float* __restrict__ colsum, float* __restrict__ delta)
{
    __shared__ __align__(16) u16 mls[64 * 264];
    __shared__ float pls[64][4][2];
    __shared__ float stat[64][2];
    int b = blockIdx.x, tid = threadIdx.x;
    int m = tid >> 2, part = tid & 3;
    const float* tp = tinit + m * 256 + part * 64;
    float* tg = tpl + (b * 64 + m) * 256 + part * 64;
    float s = 0, q2 = 0;
    for (int i = 0; i < 64; ++i) {
        float v = tp[i];
        tg[i] = v;
        s += v; q2 += v * v;
    }
    pls[m][part][0] = s; pls[m][part][1] = q2;
    __syncthreads();
    if (tid < 64) {
        float ss = 0, qq = 0;
        #pragma unroll
        for (int p = 0; p < 4; ++p) { ss += pls[tid][p][0]; qq += pls[tid][p][1]; }
        float mu = ss * (1.f / 256.f);
        float var = fmaxf(qq * (1.f / 256.f) - mu * mu, 0.f);
        stat[tid][0] = mu; stat[tid][1] = rsqrtf(var + 1e-5f);
    }
    __syncthreads();
    {
        float mu = stat[m][0], rs = stat[m][1];
        for (int i = 0; i < 64; ++i) {
            int d = part * 64 + i;
            mls[m * 264 + d] = f2bf((tp[i] - mu) * rs * ln_t_g[d] + ln_t_b[d]);
        }
    }
    __syncthreads();
    int wid = tid >> 6, lane = tid & 63, quad = lane >> 4, l15 = lane & 15;
    f32x4 qa[4][4];
    #pragma unroll
    for (int i = 0; i < 4; ++i)
        #pragma unroll
        for (int j = 0; j < 4; ++j) qa[i][j] = ZERO4;
    #pragma unroll 1
    for (int kc = 0; kc < 8; ++kc) {
        s16x8 a[4];
        #pragma unroll
        for (int fm = 0; fm < 4; ++fm)
            a[fm] = *reinterpret_cast<const s16x8*>(mls + (fm * 16 + l15) * 264 + kc * 32 + quad * 8);
        #pragma unroll
        for (int fn = 0; fn < 4; ++fn) {
            s16x8 bv = *reinterpret_cast<const s16x8*>(WqP + (wid * 64 + fn * 16 + l15) * 256 + kc * 32 + quad * 8);
            #pragma unroll
            for (int fm = 0; fm < 4; ++fm)
                qa[fm][fn] = mfma16(a[fm], bv, qa[fm][fn]);
        }
    }
    #pragma unroll
    for (int fm = 0; fm < 4; ++fm)
        #pragma unroll
        for (int fn = 0; fn < 4; ++fn)
            #pragma unroll
            for (int r = 0; r < 4; ++r) {
                int mt = fm * 16 + quad * 4 + r;
                int d = wid * 64 + fn * 16 + l15;
                qbuf[(b * 64 + mt) * 256 + d] = f2bf(qa[fm][fn][r] * 0.0625f);
            }
    if (tid < 64) colsum[b * 64 + tid] = 0.f;
    f32x4* dz = (f32x4*)(delta + b * 16384);
    for (int i = tid; i < 4096; i += 256) dz[i] = ZERO4;
}

// ============ kB: logits + softmax(over N) + colsum + attnT store ============
__global__ __launch_bounds__(256) void kB(
    const u16* __restrict__ qbuf, const u16* __restrict__ kbuf,
    u16* __restrict__ attnT, float* __restrict__ colsum)
{
    __shared__ __align__(16) u16 atile[64 * 72];
    int blk = blockIdx.x;
    int b = blk >> 6, lt = blk & 63;
    int tid = threadIdx.x, wid = tid >> 6, lane = tid & 63;
    int quad = lane >> 4, l15 = lane & 15;
    f32x4 sa[4];
    #pragma unroll
    for (int fn = 0; fn < 4; ++fn) sa[fn] = ZERO4;
    const u16* arow = kbuf + ((b << 12) + lt * 64 + wid * 16 + l15) * 256;
    const u16* qb = qbuf + b * 16384;
    #pragma unroll 1
    for (int kc = 0; kc < 8; ++kc) {
        s16x8 a = *reinterpret_cast<const s16x8*>(arow + kc * 32 + quad * 8);
        #pragma unroll
        for (int fn = 0; fn < 4; ++fn) {
            s16x8 bv = *reinterpret_cast<const s16x8*>(qb + (fn * 16 + l15) * 256 + kc * 32 + quad * 8);
            sa[fn] = mfma16(a, bv, sa[fn]);
        }
    }
    float colp[4] = {0.f, 0.f, 0.f, 0.f};
    #pragma unroll
    for (int r = 0; r < 4; ++r) {
        float mx = fmaxf(fmaxf(sa[0][r], sa[1][r]), fmaxf(sa[2][r], sa[3][r]));
        #pragma unroll
        for (int msk = 1; msk <= 8; msk <<= 1) mx = fmaxf(mx, __shfl_xor(mx, msk, 64));
        float e[4], sum = 0;
        #pragma unroll
        for (int fn = 0; fn < 4; ++fn) { e[fn] = __expf(sa[fn][r] - mx); sum += e[fn]; }
        #pragma unroll
        for (int msk = 1; msk <= 8; msk <<= 1) sum += __shfl_xor(sum, msk, 64);
        float inv = 1.f / sum;
        #pragma unroll
        for (int fn = 0; fn < 4; ++fn) {
            float p = e[fn] * inv + 1e-8f;
            sa[fn][r] = p;
            colp[fn] += p;
        }
    }
    #pragma unroll
    for (int fn = 0; fn < 4; ++fn) {
        float c = colp[fn];
        c += __shfl_xor(c, 16, 64);
        c += __shfl_xor(c, 32, 64);
        colp[fn] = c;
    }
    if (lane < 16) {
        #pragma unroll
        for (int fn = 0; fn < 4; ++fn)
            atomicAdd(&colsum[b * 64 + fn * 16 + lane], colp[fn]);
    }
    #pragma unroll
    for (int r = 0; r < 4; ++r)
        #pragma unroll
        for (int fn = 0; fn < 4; ++fn)
            atile[(fn * 16 + l15) * 72 + wid * 16 + quad * 4 + r] = f2bf(sa[fn][r]);
    __syncthreads();
    int n = tid >> 2, lo = (tid & 3) * 16;
    const u16* src = atile + n * 72 + lo;
    u16* dst = attnT + ((b * 64 + n) << 12) + lt * 64 + lo;
    *(int4*)dst = *(const int4*)src;
    *(int4*)(dst + 8) = *(const int4*)(src + 8);
}

// ============ kC: delta += attnT @ vT^T (atomic over 8 l-segments); last: out1 ============
// grid 64 = b(8) * seg(8); K = 512 per block
__global__ __launch_bounds__(256) void kC(
    const u16* __restrict__ attnT, const u16* __restrict__ vT, float* __restrict__ delta,
    const float* __restrict__ colsum, int last, float* __restrict__ out1)
{
    int blk = blockIdx.x;
    int b = blk >> 3, seg = blk & 7;
    int tid = threadIdx.x, wid = tid >> 6, lane = tid & 63;
    int quad = lane >> 4, l15 = lane & 15;
    f32x4 acc[4][4];
    #pragma unroll
    for (int i = 0; i < 4; ++i)
        #pragma unroll
        for (int j = 0; j < 4; ++j) acc[i][j] = ZERO4;
    #pragma unroll 1
    for (int kc = 0; kc < 16; ++kc) {
        int koff = seg * 512 + kc * 32 + quad * 8;
        s16x8 a[4];
        #pragma unroll
        for (int fm = 0; fm < 4; ++fm)
            a[fm] = *reinterpret_cast<const s16x8*>(attnT + ((b * 64 + fm * 16 + l15) << 12) + koff);
        #pragma unroll
        for (int fn = 0; fn < 4; ++fn) {
            s16x8 bv = *reinterpret_cast<const s16x8*>(vT + ((b * 256 + wid * 64 + fn * 16 + l15) << 12) + koff);
            #pragma unroll
            for (int fm = 0; fm < 4; ++fm)
                acc[fm][fn] = mfma16(a[fm], bv, acc[fm][fn]);
        }
    }
    #pragma unroll
    for (int fm = 0; fm < 4; ++fm)
        #pragma unroll
        for (int fn = 0; fn < 4; ++fn)
            #pragma unroll
            for (int r = 0; r < 4; ++r) {
                int nt = fm * 16 + quad * 4 + r;
                int d = wid * 64 + fn * 16 + l15;
                atomicAdd(&delta[(b * 64 + nt) * 256 + d], acc[fm][fn][r]);
            }
    if (last) {
        for (int w = tid; w < 8192; w += 256) {
            int n = w >> 7, lo4 = (w & 127) * 4;
            float ci = 1.f / colsum[b * 64 + n];
            const u16* src = attnT + ((b * 64 + n) << 12) + seg * 512 + lo4;
            f32x4 o;
            o.x = bf2f(src[0]) * ci; o.y = bf2f(src[1]) * ci;
            o.z = bf2f(src[2]) * ci; o.w = bf2f(src[3]) * ci;
            *(f32x4*)(out1 + (size_t)b * 262144 + n * 4096 + seg * 512 + lo4) = o;
        }
    }
}

// ============ kD: tpl += delta/colsum; LN_m; MLP; tpl += mlp; LN_t + q (next) ============
// grid 8 (one block per batch, owns the whole template slab)
__global__ __launch_bounds__(256) void kD(
    float* __restrict__ tpl, const float* __restrict__ delta, float* __restrict__ colsum,
    const float* __restrict__ ln_m_g, const float* __restrict__ ln_m_b,
    const u16* __restrict__ W1T, const float* __restrict__ b1,
    const u16* __restrict__ W2T, const float* __restrict__ b2,
    const float* __restrict__ ln_t_g, const float* __restrict__ ln_t_b,
    const u16* __restrict__ WqP, u16* __restrict__ qbuf,
    float* __restrict__ deltaz, int last, float* __restrict__ out0)
{
    __shared__ __align__(16) u16 mls[64 * 264];   // 33792: mbuf then tbf
    __shared__ __align__(16) u16 hid[64 * 520];   // 66560 (520-pad: bank fix)
    __shared__ float pls[64][4][2];               // 2048 (also lnred)
    __shared__ float stat[64][2];                 // 512
    int b = blockIdx.x, tid = threadIdx.x;
    int wid = tid >> 6, lane = tid & 63, quad = lane >> 4, l15 = lane & 15;
    // ---- phase 1: v = tpl + delta/colsum; LN_m -> mls ----
    {
        int m = tid >> 2, part = tid & 3;
        float cinv = 1.f / colsum[b * 64 + m];
        float* tg = tpl + (b * 64 + m) * 256 + part * 64;
        const float* dg = delta + (b * 64 + m) * 256 + part * 64;
        float s = 0, q2 = 0;
        for (int i = 0; i < 64; ++i) {
            float v = tg[i] + dg[i] * cinv;
            s += v; q2 += v * v;
        }
        pls[m][part][0] = s; pls[m][part][1] = q2;
        __syncthreads();
        if (tid < 64) {
            float ss = 0, qq = 0;
            #pragma unroll
            for (int p = 0; p < 4; ++p) { ss += pls[tid][p][0]; qq += pls[tid][p][1]; }
            float mu = ss * (1.f / 256.f);
            float var = fmaxf(qq * (1.f / 256.f) - mu * mu, 0.f);
            stat[tid][0] = mu; stat[tid][1] = rsqrtf(var + 1e-5f);
        }
        __syncthreads();
        float mu = stat[m][0], rs = stat[m][1];
        for (int i = 0; i < 64; ++i) {
            float v = tg[i] + dg[i] * cinv;
            tg[i] = v;
            int d = part * 64 + i;
            mls[m * 264 + d] = f2bf((v - mu) * rs * ln_m_g[d] + ln_m_b[d]);
        }
    }
    __syncthreads();
    // ---- G1: hid = gelu(mls @ W1 + b1) ----
    {
        f32x4 ha[4][8];
        #pragma unroll
        for (int i = 0; i < 4; ++i)
            #pragma unroll
            for (int j = 0; j < 8; ++j) ha[i][j] = ZERO4;
        #pragma unroll 1
        for (int kc = 0; kc < 8; ++kc) {
            s16x8 a[4];
            #pragma unroll
            for (int fm = 0; fm < 4; ++fm)
                a[fm] = *reinterpret_cast<const s16x8*>(mls + (fm * 16 + l15) * 264 + kc * 32 + quad * 8);
            #pragma unroll
            for (int fn = 0; fn < 8; ++fn) {
                s16x8 bv = *reinterpret_cast<const s16x8*>(W1T + (wid * 128 + fn * 16 + l15) * 256 + kc * 32 + quad * 8);
                #pragma unroll
                for (int fm = 0; fm < 4; ++fm)
                    ha[fm][fn] = mfma16(a[fm], bv, ha[fm][fn]);
            }
        }
        #pragma unroll
        for (int fm = 0; fm < 4; ++fm)
            #pragma unroll
            for (int fn = 0; fn < 8; ++fn) {
                int nh = wid * 128 + fn * 16 + l15;
                float bb = b1[nh];
                #pragma unroll
                for (int r = 0; r < 4; ++r) {
                    int mm = fm * 16 + quad * 4 + r;
                    float v = ha[fm][fn][r] + bb;
                    v = 0.5f * v * (1.f + erff(v * 0.70710678118654752f));
                    hid[mm * 520 + nh] = f2bf(v);
                }
            }
    }
    __syncthreads();
    // ---- G2: new = tpl + hid @ W2 + b2; LN_t -> mls; out0 on last ----
    {
        f32x4 oa[4][4];
        #pragma unroll
        for (int i = 0; i < 4; ++i)
            #pragma unroll
            for (int j = 0; j < 4; ++j) oa[i][j] = ZERO4;
        #pragma unroll 1
        for (int kc = 0; kc < 16; ++kc) {
            s16x8 a[4];
            #pragma unroll
            for (int fm = 0; fm < 4; ++fm)
                a[fm] = *reinterpret_cast<const s16x8*>(hid + (fm * 16 + l15) * 520 + kc * 32 + quad * 8);
            #pragma unroll
            for (int fn = 0; fn < 4; ++fn) {
                s16x8 bv = *reinterpret_cast<const s16x8*>(W2T + (wid * 64 + fn * 16 + l15) * 512 + kc * 32 + quad * 8);
                #pragma unroll
                for (int fm = 0; fm < 4; ++fm)
                    oa[fm][fn] = mfma16(a[fm], bv, oa[fm][fn]);
            }
        }
        #pragma unroll
        for (int fm = 0; fm < 4; ++fm)
            #pragma unroll
            for (int fn = 0; fn < 4; ++fn) {
                int d = wid * 64 + fn * 16 + l15;
                float bb = b2[d];
                #pragma unroll
                for (int r = 0; r < 4; ++r) {
                    int mm = fm * 16 + quad * 4 + r;
                    oa[fm][fn][r] += bb + tpl[(b * 64 + mm) * 256 + d];
                }
            }
        // LN_t stats over new templates (C-layout rows)
        float* lnred = &pls[0][0][0];
        #pragma unroll
        for (int fm = 0; fm < 4; ++fm)
            #pragma unroll
            for (int r = 0; r < 4; ++r) {
                float s = oa[fm][0][r] + oa[fm][1][r] + oa[fm][2][r] + oa[fm][3][r];
                float q2 = oa[fm][0][r] * oa[fm][0][r] + oa[fm][1][r] * oa[fm][1][r]
                         + oa[fm][2][r] * oa[fm][2][r] + oa[fm][3][r] * oa[fm][3][r];
                #pragma unroll
                for (int msk = 1; msk <= 8; msk <<= 1) {
                    s  += __shfl_xor(s, msk, 64);
                    q2 += __shfl_xor(q2, msk, 64);
                }
                if (l15 == 0) {
                    int mm = fm * 16 + quad * 4 + r;
                    lnred[(wid * 64 + mm) * 2 + 0] = s;
                    lnred[(wid * 64 + mm) * 2 + 1] = q2;
                }
            }
        __syncthreads();
        if (tid < 64) {
            float ss = 0, qq = 0;
            #pragma unroll
            for (int w = 0; w < 4; ++w) { ss += lnred[(w * 64 + tid) * 2]; qq += lnred[(w * 64 + tid) * 2 + 1]; }
            float mu = ss * (1.f / 256.f);
            float var = fmaxf(qq * (1.f / 256.f) - mu * mu, 0.f);
            stat[tid][0] = mu; stat[tid][1] = rsqrtf(var + 1e-5f);
        }
        __syncthreads();
        #pragma unroll
        for (int fm = 0; fm < 4; ++fm)
            #pragma unroll
            for (int fn = 0; fn < 4; ++fn) {
                int d = wid * 64 + fn * 16 + l15;
                float gg = last ? 0.f : ln_t_g[d];
                float bt = last ? 0.f : ln_t_b[d];
                #pragma unroll
                for (int r = 0; r < 4; ++r) {
                    int mm = fm * 16 + quad * 4 + r;
                    float v = oa[fm][fn][r];
                    tpl[(b * 64 + mm) * 256 + d] = v;
                    if (last) {
                        out0[(b * 256 + d) * 64 + mm] = v;
                    } else {
                        float mu = stat[mm][0], rs = stat[mm][1];
                        mls[mm * 264 + d] = f2bf((v - mu) * rs * gg + bt);
                    }
                }
            }
    }
    if (!last) {
        __syncthreads();
        // ---- q-GEMM for next iteration ----
        f32x4 qa[4][4];
        #pragma unroll
        for (int i = 0; i < 4; ++i)
            #pragma unroll
            for (int j = 0; j < 4; ++j) qa[i][j] = ZERO4;
        #pragma unroll 1
        for (int kc = 0; kc < 8; ++kc) {
            s16x8 a[4];
            #pragma unroll
            for (int fm = 0; fm < 4; ++fm)
                a[fm] = *reinterpret_cast<const s16x8*>(mls + (fm * 16 + l15) * 264 + kc * 32 + quad * 8);
            #pragma unroll
            for (int fn = 0; fn < 4; ++fn) {
                s16x8 bv = *reinterpret_cast<const s16x8*>(WqP + (wid * 64 + fn * 16 + l15) * 256 + kc * 32 + quad * 8);
                #pragma unroll
                for (int fm = 0; fm < 4; ++fm)
                    qa[fm][fn] = mfma16(a[fm], bv, qa[fm][fn]);
            }
        }
        #pragma unroll
        for (int fm = 0; fm < 4; ++fm)
            #pragma unroll
            for (int fn = 0; fn < 4; ++fn)
                #pragma unroll
                for (int r = 0; r < 4; ++r) {
                    int mt = fm * 16 + quad * 4 + r;
                    int d = wid * 64 + fn * 16 + l15;
                    qbuf[(b * 64 + mt) * 256 + d] = f2bf(qa[fm][fn][r] * 0.0625f);
                }
        if (tid < 64) colsum[b * 64 + tid] = 0.f;
        f32x4* dz = (f32x4*)(deltaz + b * 16384);
        for (int i = tid; i < 4096; i += 256) dz[i] = ZERO4;
    }
}

// ============ launch ============
extern "C" void kernel_launch(void* const* d_in, const int* in_sizes, int n_in,
                              void* d_out, int out_size, void* d_ws, size_t ws_size,
                              hipStream_t stream)
{
    const float* x       = (const float*)d_in[0];
    const float* tinit   = (const float*)d_in[1];
    const float* conv_w  = (const float*)d_in[2];
    const float* conv_b  = (const float*)d_in[3];
    const float* Wq      = (const float*)d_in[4];
    const float* Wk      = (const float*)d_in[5];
    const float* Wv      = (const float*)d_in[6];
    const float* ln_in_g = (const float*)d_in[7];
    const float* ln_in_b = (const float*)d_in[8];
    const float* ln_t_g  = (const float*)d_in[9];
    const float* ln_t_b  = (const float*)d_in[10];
    const float* ln_m_g  = (const float*)d_in[11];
    const float* ln_m_b  = (const float*)d_in[12];
    const float* W1      = (const float*)d_in[13];
    const float* b1      = (const float*)d_in[14];
    const float* W2      = (const float*)d_in[15];
    const float* b2      = (const float*)d_in[16];

    char* ws = (char*)d_ws;
    u16* Bp       = (u16*)(ws + 0);          // 2,359,296
    u16* WkvP     = (u16*)(ws + 2359296);    //   262,144
    u16* WqP      = (u16*)(ws + 2621440);    //   131,072
    u16* W1T      = (u16*)(ws + 2752512);    //   262,144
    u16* W2T      = (u16*)(ws + 3014656);    //   262,144
    u16* kbuf     = (u16*)(ws + 3276800);    // 16,777,216
    u16* vT       = (u16*)(ws + 20054016);   // 16,777,216
    u16* qbuf     = (u16*)(ws + 36831232);   //   262,144
    u16* attnT    = (u16*)(ws + 37093376);   // 4,194,304
    float* colsum = (float*)(ws + 41287680); //     2,048
    float* tpl    = (float*)(ws + 41289728); //   524,288
    float* delta  = (float*)(ws + 41814016); //   524,288   (total ~42.3 MB)

    float* out0 = (float*)d_out;      // templates_out (8,256,64)
    float* out1 = out0 + 131072;      // attn_out (8,64,16,16,16)

    prepack_kernel<<<2944, 256, 0, stream>>>(conv_w, Wk, Wv, Wq, W1, W2, Bp, WkvP, WqP, W1T, W2T);
    conv_fused<<<512, 256, 0, stream>>>(x, Bp, conv_b, ln_in_g, ln_in_b, WkvP, kbuf, vT);
    kQ<<<8, 256, 0, stream>>>(tinit, tpl, ln_t_g, ln_t_b, WqP, qbuf, colsum, delta);
    for (int it = 0; it < 6; ++it) {
        int last = (it == 5) ? 1 : 0;
        kB<<<512, 256, 0, stream>>>(qbuf, kbuf, attnT, colsum);
        kC<<<64, 256, 0, stream>>>(attnT, vT, delta, colsum, last, out1);
        kD<<<8, 256, 0, stream>>>(tpl, delta, colsum, ln_m_g, ln_m_b, W1T, b1, W2T, b2,
                                  ln_t_g, ln_t_b, WqP, qbuf, delta, last, out0);
    }
}